// Round 4
// baseline (1064.678 us; speedup 1.0000x reference)
//
#include <hip/hip_runtime.h>
#include <hip/hip_bf16.h>
#include <math.h>

#define NN 50000
#define EE 800000
#define HID 128
#define PED 24
#define IND 64
#define OUTD 64
#define EBLK 64          // edges per edge-kernel block
#define AKS 136          // act/W LDS k-stride in bf16 (272 B: 16B-aligned, bank-spread)

typedef short bf16x8 __attribute__((ext_vector_type(8)));
typedef float f32x4 __attribute__((ext_vector_type(4)));

__device__ __forceinline__ float gelu_exact(float x) {
    return 0.5f * x * (1.0f + erff(x * 0.70710678118654752440f));
}
__device__ __forceinline__ unsigned short f2bf(float f) {
    unsigned int u = __float_as_uint(f);
    u = (u + 0x7fffu + ((u >> 16) & 1u)) >> 16;   // RNE
    return (unsigned short)u;
}
__device__ __forceinline__ unsigned int pkbf2(float a, float b) {
    __hip_bfloat162 h = __float22bfloat162_rn(make_float2(a, b));  // a -> low
    return *reinterpret_cast<unsigned int*>(&h);
}
__device__ __forceinline__ float bf2f(unsigned short s) {
    return __uint_as_float(((unsigned int)s) << 16);
}

// ---------------------------------------------------------------------------
// xh = x @ W_x + b_x    [N, 128]
// ---------------------------------------------------------------------------
__global__ __launch_bounds__(256) void xh_kernel(
    const float* __restrict__ x, const float* __restrict__ W_x,
    const float* __restrict__ b_x, float* __restrict__ xh) {
    int gid = blockIdx.x * 256 + threadIdx.x;
    int n = gid >> 7;
    int j = gid & 127;
    if (n >= NN) return;
    const float* xr = x + (size_t)n * IND;
    float acc = b_x[j];
#pragma unroll
    for (int k = 0; k < IND; k++) acc += xr[k] * W_x[k * HID + j];
    xh[(size_t)n * HID + j] = acc;
}

// ---------------------------------------------------------------------------
// weight prep: bf16 transposed copies WT[j][k] = W[k][j] (A-operand, k-minor)
// ---------------------------------------------------------------------------
__global__ __launch_bounds__(256) void prep_kernel(
    const float* __restrict__ W_in, const float* __restrict__ W1,
    const float* __restrict__ W2, const float* __restrict__ Wf,
    unsigned short* __restrict__ WT_in, unsigned short* __restrict__ WT1,
    unsigned short* __restrict__ WT2, unsigned short* __restrict__ WTf) {
    int idx = blockIdx.x * 256 + threadIdx.x;
    if (idx < 4096) {                       // WT_in [128][32], k>=24 zero-pad
        int j = idx >> 5, k = idx & 31;
        WT_in[idx] = f2bf(k < PED ? W_in[k * HID + j] : 0.f);
    } else if (idx < 4096 + 16384) {
        int i = idx - 4096; int j = i >> 7, k = i & 127;
        WT1[i] = f2bf(W1[k * HID + j]);
    } else if (idx < 4096 + 32768) {
        int i = idx - 4096 - 16384; int j = i >> 7, k = i & 127;
        WT2[i] = f2bf(W2[k * HID + j]);
    } else if (idx < 4096 + 49152) {
        int i = idx - 4096 - 32768; int j = i >> 7, k = i & 127;
        WTf[i] = f2bf(Wf[k * HID + j]);
    }
}

// ---------------------------------------------------------------------------
// CSR build: histogram(tgt) -> exclusive scan -> scatter edge ids
// ---------------------------------------------------------------------------
__global__ __launch_bounds__(256) void hist_kernel(const int* __restrict__ pe_idx,
                                                   int* __restrict__ cnt) {
    int e = blockIdx.x * 256 + threadIdx.x;
    if (e < EE) atomicAdd(&cnt[pe_idx[e]], 1);
}

__global__ __launch_bounds__(1024) void scan_kernel(const int* __restrict__ cnt,
                                                    int* __restrict__ woff) {
    __shared__ int s_w[16];
    int tid = threadIdx.x;
    const int chunk = (NN + 1023) / 1024;
    int base = tid * chunk;
    int end = base + chunk; if (end > NN) end = NN;
    int s = 0;
    for (int i = base; i < end; i++) s += cnt[i];
    int v = s;
    int lane = tid & 63, wid = tid >> 6;
#pragma unroll
    for (int d = 1; d < 64; d <<= 1) {
        int u = __shfl_up(v, d, 64);
        if (lane >= d) v += u;
    }
    if (lane == 63) s_w[wid] = v;
    __syncthreads();
    if (tid < 16) {
        int wv = s_w[tid];
#pragma unroll
        for (int d = 1; d < 16; d <<= 1) {
            int u = __shfl_up(wv, d, 64);
            if (tid >= d) wv += u;
        }
        s_w[tid] = wv;
    }
    __syncthreads();
    int exc = v - s + (wid ? s_w[wid - 1] : 0);
    int run = exc;
    for (int i = base; i < end; i++) { woff[i] = run; run += cnt[i]; }
}

__global__ __launch_bounds__(256) void scatter_kernel(const int* __restrict__ pe_idx,
                                                      int* __restrict__ woff,
                                                      int* __restrict__ perm) {
    int e = blockIdx.x * 256 + threadIdx.x;
    if (e < EE) {
        int t = pe_idx[e];
        int p = atomicAdd(&woff[t], 1);
        perm[p] = e;
    }
}

// ---------------------------------------------------------------------------
// Fused: edge MLP on MFMA + gather-multiply + CSR-sorted segment reduction.
// Block = 256 thr (4 waves) x 64 edges. D[ch][e]: A = WT (k-minor), B =
// act[e][k] (k-minor). C layout (16x16x32): col = e = lane&15,
// row = ch = quad*4 + reg. Epilogue (threads 0..127, one per channel) walks
// the 64 CSR-sorted edges run-reducing xh[src][c]*score per node; interior
// nodes (block-owned) -> plain store; first/last segment -> atomicAdd
// (<=2 coalesced node-rows per block).
// ---------------------------------------------------------------------------
__global__ __launch_bounds__(256, 3) void edge_kernel(
    const float* __restrict__ pe_val, const int* __restrict__ pe_idx,
    const int* __restrict__ perm, const float* __restrict__ xh,
    const unsigned short* __restrict__ WT_in, const unsigned short* __restrict__ WT1,
    const unsigned short* __restrict__ WT2, const unsigned short* __restrict__ WTf,
    const float* __restrict__ b_in, const float* __restrict__ b1,
    const float* __restrict__ b2, const float* __restrict__ bfin,
    float* __restrict__ wV) {
    __shared__ unsigned short s_act[EBLK][AKS];   // 17.4 KB
    __shared__ unsigned short s_W[HID][AKS];      // 34.8 KB
    __shared__ int s_eid[EBLK], s_tgt[EBLK], s_src[EBLK];

    const int tid = threadIdx.x;
    const int lane = tid & 63;
    const int w = tid >> 6;          // wave 0..3
    const int l15 = lane & 15;
    const int quad = lane >> 4;
    const long b0 = (long)blockIdx.x * EBLK;

    if (tid < EBLK) {
        int eid = perm[b0 + tid];
        s_eid[tid] = eid;
        s_tgt[tid] = pe_idx[eid];
        s_src[tid] = pe_idx[EE + eid];
    }
    // stage W1 (used by GEMM2)
#pragma unroll
    for (int i = 0; i < 8; i++) {
        int idx = tid + i * 256; int r = idx >> 4, seg = idx & 15;
        *(uint4*)&s_W[r][seg * 8] = *(const uint4*)&WT1[r * HID + seg * 8];
    }
    __syncthreads();
    // stage pe (bf16) into act cols 0..31 (24..31 zero)
#pragma unroll
    for (int i = 0; i < 8; i++) {
        int idx = tid + i * 256; int e = idx >> 5, k = idx & 31;
        float v = (k < PED) ? pe_val[(size_t)s_eid[e] * PED + k] : 0.f;
        s_act[e][k] = f2bf(v);
    }
    __syncthreads();

    f32x4 C[2][4];
    f32x4 x0s[2][4];
    const f32x4 z4 = {0.f, 0.f, 0.f, 0.f};

    // ---- GEMM1: x0 = pe @ W_in + b_in   (K=32, one MFMA per tile) ----
    {
        bf16x8 a0 = *(const bf16x8*)&WT_in[((2 * w + 0) * 16 + l15) * 32 + quad * 8];
        bf16x8 a1 = *(const bf16x8*)&WT_in[((2 * w + 1) * 16 + l15) * 32 + quad * 8];
#pragma unroll
        for (int u = 0; u < 4; u++) {
            bf16x8 bfr = *(const bf16x8*)&s_act[u * 16 + l15][quad * 8];
            C[0][u] = __builtin_amdgcn_mfma_f32_16x16x32_bf16(a0, bfr, z4, 0, 0, 0);
            C[1][u] = __builtin_amdgcn_mfma_f32_16x16x32_bf16(a1, bfr, z4, 0, 0, 0);
        }
    }
    __syncthreads();   // act reads done
    // epilogue: +b_in, save x0, gelu -> act
#pragma unroll
    for (int t = 0; t < 2; t++) {
        int ch0 = (2 * w + t) * 16 + quad * 4;
        float4 bb = *(const float4*)&b_in[ch0];
#pragma unroll
        for (int u = 0; u < 4; u++) {
            int e = u * 16 + l15;
            f32x4 c = C[t][u];
            c[0] += bb.x; c[1] += bb.y; c[2] += bb.z; c[3] += bb.w;
            x0s[t][u] = c;
            uint2 p;
            p.x = pkbf2(gelu_exact(c[0]), gelu_exact(c[1]));
            p.y = pkbf2(gelu_exact(c[2]), gelu_exact(c[3]));
            *(uint2*)&s_act[e][ch0] = p;
        }
    }
    __syncthreads();

#define GEMM128()                                                              \
    {                                                                          \
        _Pragma("unroll") for (int t = 0; t < 2; t++)                          \
            _Pragma("unroll") for (int u = 0; u < 4; u++) C[t][u] = z4;        \
        _Pragma("unroll") for (int ks = 0; ks < 4; ks++) {                     \
            bf16x8 a0 = *(const bf16x8*)&s_W[(2 * w + 0) * 16 + l15]           \
                                            [ks * 32 + quad * 8];              \
            bf16x8 a1 = *(const bf16x8*)&s_W[(2 * w + 1) * 16 + l15]           \
                                            [ks * 32 + quad * 8];              \
            _Pragma("unroll") for (int u = 0; u < 4; u++) {                    \
                bf16x8 bfr = *(const bf16x8*)&s_act[u * 16 + l15]              \
                                                   [ks * 32 + quad * 8];       \
                C[0][u] = __builtin_amdgcn_mfma_f32_16x16x32_bf16(a0, bfr,     \
                                                                  C[0][u], 0, 0, 0); \
                C[1][u] = __builtin_amdgcn_mfma_f32_16x16x32_bf16(a1, bfr,     \
                                                                  C[1][u], 0, 0, 0); \
            }                                                                  \
        }                                                                      \
    }

#define STAGE_W(WT)                                                            \
    _Pragma("unroll") for (int i = 0; i < 8; i++) {                            \
        int idx = tid + i * 256; int r = idx >> 4, seg = idx & 15;             \
        *(uint4*)&s_W[r][seg * 8] = *(const uint4*)&(WT)[r * HID + seg * 8];   \
    }

    // ---- GEMM2: h1 = g(x0) @ W1 + b1 ; gelu -> act ; stage W2 ----
    GEMM128();
    __syncthreads();
#pragma unroll
    for (int t = 0; t < 2; t++) {
        int ch0 = (2 * w + t) * 16 + quad * 4;
        float4 bb = *(const float4*)&b1[ch0];
#pragma unroll
        for (int u = 0; u < 4; u++) {
            int e = u * 16 + l15;
            f32x4 c = C[t][u];
            uint2 p;
            p.x = pkbf2(gelu_exact(c[0] + bb.x), gelu_exact(c[1] + bb.y));
            p.y = pkbf2(gelu_exact(c[2] + bb.z), gelu_exact(c[3] + bb.w));
            *(uint2*)&s_act[e][ch0] = p;
        }
    }
    STAGE_W(WT2);
    __syncthreads();

    // ---- GEMM3: h2 = g(h1) @ W2 + b2 ; x0' = h2 + x0 -> act ; stage Wf ----
    GEMM128();
    __syncthreads();
#pragma unroll
    for (int t = 0; t < 2; t++) {
        int ch0 = (2 * w + t) * 16 + quad * 4;
        float4 bb = *(const float4*)&b2[ch0];
#pragma unroll
        for (int u = 0; u < 4; u++) {
            int e = u * 16 + l15;
            f32x4 c = C[t][u];
            f32x4 x0 = x0s[t][u];
            uint2 p;
            p.x = pkbf2(c[0] + bb.x + x0[0], c[1] + bb.y + x0[1]);
            p.y = pkbf2(c[2] + bb.z + x0[2], c[3] + bb.w + x0[3]);
            *(uint2*)&s_act[e][ch0] = p;
        }
    }
    STAGE_W(WTf);
    __syncthreads();

    // ---- GEMM4: score = x0' @ W_fin + b_fin -> act (bf16) ----
    GEMM128();
    __syncthreads();
#pragma unroll
    for (int t = 0; t < 2; t++) {
        int ch0 = (2 * w + t) * 16 + quad * 4;
        float4 bb = *(const float4*)&bfin[ch0];
#pragma unroll
        for (int u = 0; u < 4; u++) {
            int e = u * 16 + l15;
            f32x4 c = C[t][u];
            uint2 p;
            p.x = pkbf2(c[0] + bb.x, c[1] + bb.y);
            p.y = pkbf2(c[2] + bb.z, c[3] + bb.w);
            *(uint2*)&s_act[e][ch0] = p;
        }
    }
    __syncthreads();

    // ---- fused aggregation: threads 0..127 = one channel each ----
    if (tid < HID) {
        const int c = tid;
        float acc = 0.f;
        int prev = s_tgt[0];
        bool firstseg = true;
#pragma unroll 8
        for (int e = 0; e < EBLK; e++) {
            int t = s_tgt[e];
            if (t != prev) {
                if (firstseg) atomicAdd(&wV[(size_t)prev * HID + c], acc);
                else          wV[(size_t)prev * HID + c] = acc;
                firstseg = false;
                acc = 0.f;
                prev = t;
            }
            acc += xh[(size_t)s_src[e] * HID + c] * bf2f(s_act[e][c]);
        }
        atomicAdd(&wV[(size_t)prev * HID + c], acc);  // last seg may be shared
    }
#undef GEMM128
#undef STAGE_W
}

// ---------------------------------------------------------------------------
// out = (wV / max(deg,1) + head_bias) @ W_out + b_out   [N, 64]
// ---------------------------------------------------------------------------
__global__ __launch_bounds__(256) void out_kernel(
    const float* __restrict__ wV, const int* __restrict__ cnt,
    const float* __restrict__ head_bias, const float* __restrict__ W_out,
    const float* __restrict__ b_out, float* __restrict__ out) {
    int gid = blockIdx.x * 256 + threadIdx.x;
    int n = gid >> 6;
    int jo = gid & 63;
    if (n >= NN) return;
    float inv = 1.0f / fmaxf((float)cnt[n], 1.0f);
    const float* wr = wV + (size_t)n * HID;
    float acc = b_out[jo];
#pragma unroll
    for (int k = 0; k < HID; k++) {
        float hv = wr[k] * inv + head_bias[k];
        acc += hv * W_out[k * OUTD + jo];
    }
    out[(size_t)n * OUTD + jo] = acc;
}

extern "C" void kernel_launch(void* const* d_in, const int* in_sizes, int n_in,
                              void* d_out, int out_size, void* d_ws, size_t ws_size,
                              hipStream_t stream) {
    const float* x      = (const float*)d_in[0];
    const int*   pe_idx = (const int*)d_in[1];
    const float* pe_val = (const float*)d_in[2];
    const float* W_in   = (const float*)d_in[3];
    const float* b_in   = (const float*)d_in[4];
    const float* W1     = (const float*)d_in[5];
    const float* b1     = (const float*)d_in[6];
    const float* W2     = (const float*)d_in[7];
    const float* b2     = (const float*)d_in[8];
    const float* Wf     = (const float*)d_in[9];
    const float* bfin   = (const float*)d_in[10];
    const float* W_x    = (const float*)d_in[11];
    const float* b_x    = (const float*)d_in[12];
    const float* hb     = (const float*)d_in[13];
    const float* W_out  = (const float*)d_in[14];
    const float* b_out  = (const float*)d_in[15];
    float* out = (float*)d_out;

    // ws layout (dwords):
    // xh 6.4M | wV 6.4M | cnt 50k | woff 50k | perm 800k | WT_in 2048 |
    // WT1 8192 | WT2 8192 | WTf 8192
    float* xh   = (float*)d_ws;
    float* wV   = xh + (size_t)NN * HID;
    int*   cnt  = (int*)(wV + (size_t)NN * HID);
    int*   woff = cnt + NN;
    int*   perm = woff + NN;
    unsigned short* WT_in = (unsigned short*)(perm + EE);
    unsigned short* WT1   = WT_in + 128 * 32;
    unsigned short* WT2   = WT1 + 128 * 128;
    unsigned short* WTf   = WT2 + 128 * 128;

    // zero wV + cnt (contiguous)
    hipMemsetAsync(wV, 0, ((size_t)NN * HID + NN) * sizeof(float), stream);

    hist_kernel<<<(EE + 255) / 256, 256, 0, stream>>>(pe_idx, cnt);
    scan_kernel<<<1, 1024, 0, stream>>>(cnt, woff);
    scatter_kernel<<<(EE + 255) / 256, 256, 0, stream>>>(pe_idx, woff, perm);
    prep_kernel<<<208, 256, 0, stream>>>(W_in, W1, W2, Wf, WT_in, WT1, WT2, WTf);
    xh_kernel<<<(NN * HID + 255) / 256, 256, 0, stream>>>(x, W_x, b_x, xh);

    edge_kernel<<<EE / EBLK, 256, 0, stream>>>(pe_val, pe_idx, perm, xh,
                                               WT_in, WT1, WT2, WTf,
                                               b_in, b1, b2, bfin, wV);

    out_kernel<<<(NN * OUTD + 255) / 256, 256, 0, stream>>>(wV, cnt, hb, W_out,
                                                            b_out, out);
}

// Round 5
// 697.782 us; speedup vs baseline: 1.5258x; 1.5258x over previous
//
#include <hip/hip_runtime.h>
#include <hip/hip_bf16.h>
#include <math.h>

#define NN 50000
#define EE 800000
#define HID 128
#define PED 24
#define IND 64
#define OUTD 64
#define EBLK 64          // edges per edge-kernel block
#define AKS 136          // act/W LDS k-stride in bf16 (272 B: 16B-aligned, bank-spread)

typedef short bf16x8 __attribute__((ext_vector_type(8)));
typedef float f32x4 __attribute__((ext_vector_type(4)));

// Fast exact-erf GELU: A&S 7.1.26, |erf err| <= 1.5e-7 (far below bf16 noise).
// ~15 VALU ops vs ~30+ for libm erff.
__device__ __forceinline__ float gelu_fast(float x) {
    float z = fabsf(x) * 0.70710678118654752440f;
    float t = __builtin_amdgcn_rcpf(1.0f + 0.3275911f * z);
    float poly = t * (0.254829592f +
                 t * (-0.284496736f +
                 t * (1.421413741f +
                 t * (-1.453152027f +
                 t * 1.061405429f))));
    float e = __expf(-z * z);
    float erfa = 1.0f - poly * e;          // erf(|x|/sqrt2)
    float s = copysignf(erfa, x);
    return 0.5f * x * (1.0f + s);
}
__device__ __forceinline__ unsigned short f2bf(float f) {
    unsigned int u = __float_as_uint(f);
    u = (u + 0x7fffu + ((u >> 16) & 1u)) >> 16;   // RNE
    return (unsigned short)u;
}
__device__ __forceinline__ unsigned int pkbf2(float a, float b) {
    __hip_bfloat162 h = __float22bfloat162_rn(make_float2(a, b));  // a -> low
    return *reinterpret_cast<unsigned int*>(&h);
}
__device__ __forceinline__ float bflo(unsigned int u) {
    return __uint_as_float(u << 16);
}
__device__ __forceinline__ float bfhi(unsigned int u) {
    return __uint_as_float(u & 0xffff0000u);
}

// ---------------------------------------------------------------------------
// xh_bf16 = bf16(x @ W_x + b_x)    [N, 128]; 4 ch/thread, float4 W loads
// ---------------------------------------------------------------------------
__global__ __launch_bounds__(256) void xh_kernel(
    const float* __restrict__ x, const float* __restrict__ W_x,
    const float* __restrict__ b_x, unsigned short* __restrict__ xhb) {
    int gid = blockIdx.x * 256 + threadIdx.x;
    int n = gid >> 5;
    int q = gid & 31;
    if (n >= NN) return;
    const float* xr = x + (size_t)n * IND;
    float4 acc = *(const float4*)&b_x[q * 4];
#pragma unroll 8
    for (int k = 0; k < IND; k++) {
        float xk = xr[k];
        float4 w = *(const float4*)&W_x[k * HID + q * 4];
        acc.x += xk * w.x; acc.y += xk * w.y;
        acc.z += xk * w.z; acc.w += xk * w.w;
    }
    uint2 p;
    p.x = pkbf2(acc.x, acc.y);
    p.y = pkbf2(acc.z, acc.w);
    ((uint2*)&xhb[(size_t)n * HID])[q] = p;
}

// ---------------------------------------------------------------------------
// weight prep: bf16 transposed copies WT[j][k] = W[k][j] (A-operand, k-minor)
// ---------------------------------------------------------------------------
__global__ __launch_bounds__(256) void prep_kernel(
    const float* __restrict__ W_in, const float* __restrict__ W1,
    const float* __restrict__ W2, const float* __restrict__ Wf,
    unsigned short* __restrict__ WT_in, unsigned short* __restrict__ WT1,
    unsigned short* __restrict__ WT2, unsigned short* __restrict__ WTf) {
    int idx = blockIdx.x * 256 + threadIdx.x;
    if (idx < 4096) {                       // WT_in [128][32], k>=24 zero-pad
        int j = idx >> 5, k = idx & 31;
        WT_in[idx] = f2bf(k < PED ? W_in[k * HID + j] : 0.f);
    } else if (idx < 4096 + 16384) {
        int i = idx - 4096; int j = i >> 7, k = i & 127;
        WT1[i] = f2bf(W1[k * HID + j]);
    } else if (idx < 4096 + 32768) {
        int i = idx - 4096 - 16384; int j = i >> 7, k = i & 127;
        WT2[i] = f2bf(W2[k * HID + j]);
    } else if (idx < 4096 + 49152) {
        int i = idx - 4096 - 32768; int j = i >> 7, k = i & 127;
        WTf[i] = f2bf(Wf[k * HID + j]);
    }
}

// ---------------------------------------------------------------------------
// CSR build: histogram(tgt) -> exclusive scan -> scatter edge ids
// ---------------------------------------------------------------------------
__global__ __launch_bounds__(256) void hist_kernel(const int* __restrict__ pe_idx,
                                                   int* __restrict__ cnt) {
    int e = blockIdx.x * 256 + threadIdx.x;
    if (e < EE) atomicAdd(&cnt[pe_idx[e]], 1);
}

__global__ __launch_bounds__(1024) void scan_kernel(const int* __restrict__ cnt,
                                                    int* __restrict__ woff) {
    __shared__ int s_w[16];
    int tid = threadIdx.x;
    const int chunk = (NN + 1023) / 1024;
    int base = tid * chunk;
    int end = base + chunk; if (end > NN) end = NN;
    int s = 0;
    for (int i = base; i < end; i++) s += cnt[i];
    int v = s;
    int lane = tid & 63, wid = tid >> 6;
#pragma unroll
    for (int d = 1; d < 64; d <<= 1) {
        int u = __shfl_up(v, d, 64);
        if (lane >= d) v += u;
    }
    if (lane == 63) s_w[wid] = v;
    __syncthreads();
    if (tid < 16) {
        int wv = s_w[tid];
#pragma unroll
        for (int d = 1; d < 16; d <<= 1) {
            int u = __shfl_up(wv, d, 64);
            if (tid >= d) wv += u;
        }
        s_w[tid] = wv;
    }
    __syncthreads();
    int exc = v - s + (wid ? s_w[wid - 1] : 0);
    int run = exc;
    for (int i = base; i < end; i++) { woff[i] = run; run += cnt[i]; }
}

__global__ __launch_bounds__(256) void scatter_kernel(const int* __restrict__ pe_idx,
                                                      int* __restrict__ woff,
                                                      int* __restrict__ perm) {
    int e = blockIdx.x * 256 + threadIdx.x;
    if (e < EE) {
        int t = pe_idx[e];
        int p = atomicAdd(&woff[t], 1);
        perm[p] = e;
    }
}

// ---------------------------------------------------------------------------
// Fused: edge MLP on MFMA + gather-multiply + CSR-sorted segment reduction.
// Epilogue is two-phase: (A) all 256 threads compute msg = xh_bf16[src]*score
// with 8 independent pipelined gathers each -> s_msg (LDS, aliases dead s_W);
// (B) per-channel segment walk over LDS; first/last segment of each 32-edge
// half -> atomicAdd, interior segments (block-owned nodes) -> plain store.
// ---------------------------------------------------------------------------
__global__ __launch_bounds__(256, 3) void edge_kernel(
    const float* __restrict__ pe_val, const int* __restrict__ pe_idx,
    const int* __restrict__ perm, const unsigned short* __restrict__ xhb,
    const unsigned short* __restrict__ WT_in, const unsigned short* __restrict__ WT1,
    const unsigned short* __restrict__ WT2, const unsigned short* __restrict__ WTf,
    const float* __restrict__ b_in, const float* __restrict__ b1,
    const float* __restrict__ b2, const float* __restrict__ bfin,
    float* __restrict__ wV) {
    __shared__ unsigned short s_act[EBLK][AKS];              // 17.4 KB
    __shared__ __align__(16) unsigned short s_W[HID][AKS];   // 34.8 KB
    __shared__ int s_eid[EBLK], s_tgt[EBLK], s_src[EBLK];
    float* s_msg = (float*)&s_W[0][0];   // reused after GEMM4 (64*128 f32 = 32 KB)

    const int tid = threadIdx.x;
    const int lane = tid & 63;
    const int w = tid >> 6;          // wave 0..3
    const int l15 = lane & 15;
    const int quad = lane >> 4;
    const long b0 = (long)blockIdx.x * EBLK;

    if (tid < EBLK) {
        int eid = perm[b0 + tid];
        s_eid[tid] = eid;
        s_tgt[tid] = pe_idx[eid];
        s_src[tid] = pe_idx[EE + eid];
    }
    // stage W1 (used by GEMM2)
#pragma unroll
    for (int i = 0; i < 8; i++) {
        int idx = tid + i * 256; int r = idx >> 4, seg = idx & 15;
        *(uint4*)&s_W[r][seg * 8] = *(const uint4*)&WT1[r * HID + seg * 8];
    }
    __syncthreads();
    // stage pe (bf16) into act cols 0..31 (24..31 zero)
#pragma unroll
    for (int i = 0; i < 8; i++) {
        int idx = tid + i * 256; int e = idx >> 5, k = idx & 31;
        float v = (k < PED) ? pe_val[(size_t)s_eid[e] * PED + k] : 0.f;
        s_act[e][k] = f2bf(v);
    }
    __syncthreads();

    f32x4 C[2][4];
    f32x4 x0s[2][4];
    const f32x4 z4 = {0.f, 0.f, 0.f, 0.f};

    // ---- GEMM1: x0 = pe @ W_in + b_in   (K=32, one MFMA per tile) ----
    {
        bf16x8 a0 = *(const bf16x8*)&WT_in[((2 * w + 0) * 16 + l15) * 32 + quad * 8];
        bf16x8 a1 = *(const bf16x8*)&WT_in[((2 * w + 1) * 16 + l15) * 32 + quad * 8];
#pragma unroll
        for (int u = 0; u < 4; u++) {
            bf16x8 bfr = *(const bf16x8*)&s_act[u * 16 + l15][quad * 8];
            C[0][u] = __builtin_amdgcn_mfma_f32_16x16x32_bf16(a0, bfr, z4, 0, 0, 0);
            C[1][u] = __builtin_amdgcn_mfma_f32_16x16x32_bf16(a1, bfr, z4, 0, 0, 0);
        }
    }
    __syncthreads();   // act reads done
    // epilogue: +b_in, save x0, gelu -> act
#pragma unroll
    for (int t = 0; t < 2; t++) {
        int ch0 = (2 * w + t) * 16 + quad * 4;
        float4 bb = *(const float4*)&b_in[ch0];
#pragma unroll
        for (int u = 0; u < 4; u++) {
            int e = u * 16 + l15;
            f32x4 c = C[t][u];
            c[0] += bb.x; c[1] += bb.y; c[2] += bb.z; c[3] += bb.w;
            x0s[t][u] = c;
            uint2 p;
            p.x = pkbf2(gelu_fast(c[0]), gelu_fast(c[1]));
            p.y = pkbf2(gelu_fast(c[2]), gelu_fast(c[3]));
            *(uint2*)&s_act[e][ch0] = p;
        }
    }
    __syncthreads();

#define GEMM128()                                                              \
    {                                                                          \
        _Pragma("unroll") for (int t = 0; t < 2; t++)                          \
            _Pragma("unroll") for (int u = 0; u < 4; u++) C[t][u] = z4;        \
        _Pragma("unroll") for (int ks = 0; ks < 4; ks++) {                     \
            bf16x8 a0 = *(const bf16x8*)&s_W[(2 * w + 0) * 16 + l15]           \
                                            [ks * 32 + quad * 8];              \
            bf16x8 a1 = *(const bf16x8*)&s_W[(2 * w + 1) * 16 + l15]           \
                                            [ks * 32 + quad * 8];              \
            _Pragma("unroll") for (int u = 0; u < 4; u++) {                    \
                bf16x8 bfr = *(const bf16x8*)&s_act[u * 16 + l15]              \
                                                   [ks * 32 + quad * 8];       \
                C[0][u] = __builtin_amdgcn_mfma_f32_16x16x32_bf16(a0, bfr,     \
                                                                  C[0][u], 0, 0, 0); \
                C[1][u] = __builtin_amdgcn_mfma_f32_16x16x32_bf16(a1, bfr,     \
                                                                  C[1][u], 0, 0, 0); \
            }                                                                  \
        }                                                                      \
    }

#define STAGE_W(WT)                                                            \
    _Pragma("unroll") for (int i = 0; i < 8; i++) {                            \
        int idx = tid + i * 256; int r = idx >> 4, seg = idx & 15;             \
        *(uint4*)&s_W[r][seg * 8] = *(const uint4*)&(WT)[r * HID + seg * 8];   \
    }

    // ---- GEMM2: h1 = g(x0) @ W1 + b1 ; gelu -> act ; stage W2 ----
    GEMM128();
    __syncthreads();
#pragma unroll
    for (int t = 0; t < 2; t++) {
        int ch0 = (2 * w + t) * 16 + quad * 4;
        float4 bb = *(const float4*)&b1[ch0];
#pragma unroll
        for (int u = 0; u < 4; u++) {
            int e = u * 16 + l15;
            f32x4 c = C[t][u];
            uint2 p;
            p.x = pkbf2(gelu_fast(c[0] + bb.x), gelu_fast(c[1] + bb.y));
            p.y = pkbf2(gelu_fast(c[2] + bb.z), gelu_fast(c[3] + bb.w));
            *(uint2*)&s_act[e][ch0] = p;
        }
    }
    STAGE_W(WT2);
    __syncthreads();

    // ---- GEMM3: h2 = g(h1) @ W2 + b2 ; x0' = h2 + x0 -> act ; stage Wf ----
    GEMM128();
    __syncthreads();
#pragma unroll
    for (int t = 0; t < 2; t++) {
        int ch0 = (2 * w + t) * 16 + quad * 4;
        float4 bb = *(const float4*)&b2[ch0];
#pragma unroll
        for (int u = 0; u < 4; u++) {
            int e = u * 16 + l15;
            f32x4 c = C[t][u];
            f32x4 x0 = x0s[t][u];
            uint2 p;
            p.x = pkbf2(c[0] + bb.x + x0[0], c[1] + bb.y + x0[1]);
            p.y = pkbf2(c[2] + bb.z + x0[2], c[3] + bb.w + x0[3]);
            *(uint2*)&s_act[e][ch0] = p;
        }
    }
    STAGE_W(WTf);
    __syncthreads();

    // ---- GEMM4: score = x0' @ W_fin + b_fin -> act (bf16) ----
    GEMM128();
    __syncthreads();
#pragma unroll
    for (int t = 0; t < 2; t++) {
        int ch0 = (2 * w + t) * 16 + quad * 4;
        float4 bb = *(const float4*)&bfin[ch0];
#pragma unroll
        for (int u = 0; u < 4; u++) {
            int e = u * 16 + l15;
            f32x4 c = C[t][u];
            uint2 p;
            p.x = pkbf2(c[0] + bb.x, c[1] + bb.y);
            p.y = pkbf2(c[2] + bb.z, c[3] + bb.w);
            *(uint2*)&s_act[e][ch0] = p;
        }
    }
    __syncthreads();   // scores ready; s_W reads done -> s_msg reuse safe

    // ---- Phase A: msg[e][c] = xh_bf16[src[e]][c] * score[e][c] -> s_msg ----
    // 8 independent gathers per thread, fully pipelined.
#pragma unroll
    for (int i = 0; i < 8; i++) {
        int idx = tid + i * 256;          // 0..2047 = 64 edges x 32 chunks
        int e = idx >> 5, c4 = idx & 31;
        int src = s_src[e];
        uint2 xv = ((const uint2*)&xhb[(size_t)src * HID])[c4];
        uint2 sv = *(const uint2*)&s_act[e][c4 * 4];
        float4 m;
        m.x = bflo(xv.x) * bflo(sv.x);
        m.y = bfhi(xv.x) * bfhi(sv.x);
        m.z = bflo(xv.y) * bflo(sv.y);
        m.w = bfhi(xv.y) * bfhi(sv.y);
        *(float4*)&s_msg[e * HID + c4 * 4] = m;
    }
    __syncthreads();

    // ---- Phase B: per-channel segment walk (two 32-edge halves) ----
    {
        const int h = tid >> 7;          // half 0/1
        const int c = tid & 127;         // channel
        const int e0h = h * 32;
        float acc = 0.f;
        int prev = s_tgt[e0h];
        bool firstseg = true;
        for (int e = e0h; e < e0h + 32; e++) {
            int t = s_tgt[e];
            if (t != prev) {
                if (firstseg) atomicAdd(&wV[(size_t)prev * HID + c], acc);
                else          wV[(size_t)prev * HID + c] = acc;
                firstseg = false;
                acc = 0.f;
                prev = t;
            }
            acc += s_msg[e * HID + c];
        }
        atomicAdd(&wV[(size_t)prev * HID + c], acc);  // last seg may be shared
    }
#undef GEMM128
#undef STAGE_W
}

// ---------------------------------------------------------------------------
// out = (wV / max(deg,1) + head_bias) @ W_out + b_out ; 4 outputs/thread
// ---------------------------------------------------------------------------
__global__ __launch_bounds__(256) void out_kernel(
    const float* __restrict__ wV, const int* __restrict__ cnt,
    const float* __restrict__ head_bias, const float* __restrict__ W_out,
    const float* __restrict__ b_out, float* __restrict__ out) {
    int gid = blockIdx.x * 256 + threadIdx.x;
    int n = gid >> 4;
    int q = gid & 15;
    if (n >= NN) return;
    float inv = 1.0f / fmaxf((float)cnt[n], 1.0f);
    const float* wr = wV + (size_t)n * HID;
    float4 acc = *(const float4*)&b_out[q * 4];
#pragma unroll 4
    for (int k = 0; k < HID; k++) {
        float hv = wr[k] * inv + head_bias[k];
        float4 wv4 = *(const float4*)&W_out[k * OUTD + q * 4];
        acc.x += hv * wv4.x; acc.y += hv * wv4.y;
        acc.z += hv * wv4.z; acc.w += hv * wv4.w;
    }
    *(float4*)&out[(size_t)n * OUTD + q * 4] = acc;
}

extern "C" void kernel_launch(void* const* d_in, const int* in_sizes, int n_in,
                              void* d_out, int out_size, void* d_ws, size_t ws_size,
                              hipStream_t stream) {
    const float* x      = (const float*)d_in[0];
    const int*   pe_idx = (const int*)d_in[1];
    const float* pe_val = (const float*)d_in[2];
    const float* W_in   = (const float*)d_in[3];
    const float* b_in   = (const float*)d_in[4];
    const float* W1     = (const float*)d_in[5];
    const float* b1     = (const float*)d_in[6];
    const float* W2     = (const float*)d_in[7];
    const float* b2     = (const float*)d_in[8];
    const float* Wf     = (const float*)d_in[9];
    const float* bfin   = (const float*)d_in[10];
    const float* W_x    = (const float*)d_in[11];
    const float* b_x    = (const float*)d_in[12];
    const float* hb     = (const float*)d_in[13];
    const float* W_out  = (const float*)d_in[14];
    const float* b_out  = (const float*)d_in[15];
    float* out = (float*)d_out;

    // ws layout:
    // wV f32 [N*128] | cnt i32 [N] | woff i32 [N] | perm i32 [E] |
    // WT_in u16 [4096] | WT1/WT2/WTf u16 [16384 each] | xhb u16 [N*128]
    float* wV   = (float*)d_ws;
    int*   cnt  = (int*)(wV + (size_t)NN * HID);
    int*   woff = cnt + NN;
    int*   perm = woff + NN;
    unsigned short* WT_in = (unsigned short*)(perm + EE);
    unsigned short* WT1   = WT_in + 128 * 32;
    unsigned short* WT2   = WT1 + 128 * 128;
    unsigned short* WTf   = WT2 + 128 * 128;
    unsigned short* xhb   = WTf + 128 * 128;

    // zero wV + cnt (contiguous)
    hipMemsetAsync(wV, 0, ((size_t)NN * HID + NN) * sizeof(float), stream);

    hist_kernel<<<(EE + 255) / 256, 256, 0, stream>>>(pe_idx, cnt);
    scan_kernel<<<1, 1024, 0, stream>>>(cnt, woff);
    scatter_kernel<<<(EE + 255) / 256, 256, 0, stream>>>(pe_idx, woff, perm);
    prep_kernel<<<208, 256, 0, stream>>>(W_in, W1, W2, Wf, WT_in, WT1, WT2, WTf);
    xh_kernel<<<(NN * 32 + 255) / 256, 256, 0, stream>>>(x, W_x, b_x, xhb);

    edge_kernel<<<EE / EBLK, 256, 0, stream>>>(pe_val, pe_idx, perm, xhb,
                                               WT_in, WT1, WT2, WTf,
                                               b_in, b1, b2, bfin, wV);

    out_kernel<<<(NN * 16 + 255) / 256, 256, 0, stream>>>(wV, cnt, hb, W_out,
                                                          b_out, out);
}